// Round 1
// baseline (1043.638 us; speedup 1.0000x reference)
//
#include <hip/hip_runtime.h>
#include <math.h>
#include <stdint.h>

#define B_SZ   8
#define T_SEQ  2048
#define DIM    256
#define NH     32            // B*E
#define DE     64
#define BAND   509           // |j-i|<=509 can have nonzero f32 punish (denormals)
#define PD_N   (2*BAND + 1)
#define M_ROWS (B_SZ * T_SEQ)

// ---------------- punish table (f32-denormal-faithful, stored as double) -----
__global__ __launch_bounds__(256) void pd_kernel(double* __restrict__ pd,
                                                 const float* __restrict__ theta) {
    int i = blockIdx.x * 256 + threadIdx.x;
    if (i >= PD_N) return;
    float df  = (float)(i - BAND);
    float th  = theta[0];
    float arg = (-(df * df)) / (th * th);      // exact same f32 ops as numpy
    double pdd = exp((double)arg);
    double outv;
    if (pdd < 1.17549435082228751e-38) {
        // emulate f32 RNE rounding into the denormal range (no FTZ dependence)
        outv = rint(pdd * 0x1p149) * 0x1p-149;
    } else {
        outv = (double)(float)pdd;
    }
    pd[i] = outv;
}

// ---------------- shared 64x64 fp32 GEMM core: acc = A[m,:] . W[n,:] --------
// micro-tile rows m0+tr+16i, cols n0+tc+16j (strided to avoid LDS conflicts)
__device__ __forceinline__ void gemm64(const float* __restrict__ A,
                                       const float* __restrict__ W,
                                       int m0, int n0, int tid,
                                       float acc[4][4],
                                       float (*As)[20], float (*Ws)[20])
{
    const int srow = tid >> 2;
    const int scol = (tid & 3) << 2;
    const int tr = tid >> 4;
    const int tc = tid & 15;
    for (int k0 = 0; k0 < DIM; k0 += 16) {
        float4 av = *(const float4*)(A + (size_t)(m0 + srow) * DIM + k0 + scol);
        float4 wv = *(const float4*)(W + (size_t)(n0 + srow) * DIM + k0 + scol);
        __syncthreads();
        *(float4*)&As[srow][scol] = av;
        *(float4*)&Ws[srow][scol] = wv;
        __syncthreads();
        #pragma unroll
        for (int kk = 0; kk < 16; kk += 4) {
            float4 a[4], w[4];
            #pragma unroll
            for (int i = 0; i < 4; ++i) a[i] = *(const float4*)&As[tr + 16*i][kk];
            #pragma unroll
            for (int j = 0; j < 4; ++j) w[j] = *(const float4*)&Ws[tc + 16*j][kk];
            #pragma unroll
            for (int i = 0; i < 4; ++i)
                #pragma unroll
                for (int j = 0; j < 4; ++j)
                    acc[i][j] += a[i].x*w[j].x + a[i].y*w[j].y
                               + a[i].z*w[j].z + a[i].w*w[j].w;
        }
    }
}

// ---------------- QKV projection: Y = x@W^T + b, scatter to head layout -----
// Q[h,q,e] = Y[b,t,d], h=b*4+d/64, q=(d%64)*32+t/64, e=t%64; Q,K masked q>=sl
__global__ __launch_bounds__(256) void proj_qkv_kernel(
    const float* __restrict__ x,
    const float* __restrict__ wq, const float* __restrict__ bq,
    const float* __restrict__ wk, const float* __restrict__ bk,
    const float* __restrict__ wv, const float* __restrict__ bv,
    const int* __restrict__ seq_len,
    float* __restrict__ Qb, float* __restrict__ Kb, float* __restrict__ Vb)
{
    __shared__ float As[64][20];
    __shared__ float Ws[64][20];
    const int mode = blockIdx.z;                // 0:Q 1:K 2:V
    const float* W    = (mode == 0) ? wq : (mode == 1) ? wk : wv;
    const float* bias = (mode == 0) ? bq : (mode == 1) ? bk : bv;
    float* outp       = (mode == 0) ? Qb : (mode == 1) ? Kb : Vb;
    const int tid = threadIdx.x;
    const int m0 = blockIdx.x * 64;
    const int n0 = blockIdx.y * 64;
    float acc[4][4] = {};
    gemm64(x, W, m0, n0, tid, acc, As, Ws);
    const int tr = tid >> 4, tc = tid & 15;
    #pragma unroll
    for (int i = 0; i < 4; ++i) {
        int m  = m0 + tr + 16*i;
        int b  = m >> 11;
        int t  = m & (T_SEQ - 1);
        int sl = seq_len[b];
        int e = t & 63, thi = t >> 6;
        #pragma unroll
        for (int j = 0; j < 4; ++j) {
            int n = n0 + tc + 16*j;
            int h = b*4 + (n >> 6);
            int q = (n & 63)*32 + thi;
            float v = acc[i][j] + bias[n];
            if (mode <= 1 && q >= sl) v = 0.0f;
            outp[(((size_t)h*T_SEQ + q) << 6) + e] = v;
        }
    }
}

// ---------------- per-head mean of V over attention axis --------------------
__global__ __launch_bounds__(256) void meanv_kernel(const float* __restrict__ Vb,
                                                    float* __restrict__ mv) {
    __shared__ float red[4][64];
    int h = blockIdx.x;
    int e = threadIdx.x & 63;
    int ch = threadIdx.x >> 6;
    const float* p = Vb + (size_t)h*T_SEQ*DE + (size_t)ch*512*DE + e;
    float s0=0.f, s1=0.f, s2=0.f, s3=0.f;
    for (int q = 0; q < 512; q += 4) {
        s0 += p[(q+0)*DE]; s1 += p[(q+1)*DE];
        s2 += p[(q+2)*DE]; s3 += p[(q+3)*DE];
    }
    red[ch][e] = (s0+s1)+(s2+s3);
    __syncthreads();
    if (ch == 0)
        mv[h*DE + e] = (red[0][e]+red[1][e]+red[2][e]+red[3][e]) * (1.0f/T_SEQ);
}

// ---------------- banded flash attention (fp32), 32 q-rows/block ------------
__global__ __launch_bounds__(256) void attn_kernel(
    const float* __restrict__ Qb, const float* __restrict__ Kb,
    const float* __restrict__ Vb, const double* __restrict__ pd,
    const float* __restrict__ meanv, const int* __restrict__ seq_len,
    float* __restrict__ ctxb)
{
    __shared__ float Qs[32][68];
    __shared__ float Ks[64][68];
    __shared__ float Vs[64][68];
    __shared__ float Ps[32][68];
    const int tid = threadIdx.x;
    const int h  = blockIdx.y;
    const int b  = h >> 2;
    const int q0 = blockIdx.x * 32;
    const int sl = seq_len[b];
    const int tr = tid >> 5;     // 0..7 -> rows tr*4+i
    const int tc = tid & 31;     // j/c lanes: {tc, tc+32}
    const float scale = sqrtf((float)T_SEQ);
    float* outbase = ctxb + (size_t)b*T_SEQ*DIM + (size_t)(h & 3)*64;

    if (q0 >= sl) {   // whole tile masked: softmax uniform over ALL 2048 -> meanV
        #pragma unroll
        for (int i = 0; i < 4; ++i) {
            int q = q0 + tr*4 + i;
            outbase[(size_t)q*DIM + tc]      = meanv[h*DE + tc];
            outbase[(size_t)q*DIM + tc + 32] = meanv[h*DE + tc + 32];
        }
        return;
    }

    {   // stage Q tile
        const float* src = Qb + (size_t)h*T_SEQ*DE + (size_t)q0*DE;
        #pragma unroll
        for (int rep = 0; rep < 2; ++rep) {
            int f = rep*256 + tid;
            int row = f >> 4, c4 = (f & 15) << 2;
            *(float4*)&Qs[row][c4] = *(const float4*)(src + row*DE + c4);
        }
    }

    float m_i[4], l_i[4], cacc[4][2];
    #pragma unroll
    for (int i = 0; i < 4; ++i) { m_i[i] = -2e20f; l_i[i] = 0.f; cacc[i][0] = 0.f; cacc[i][1] = 0.f; }

    int jlo = q0 - BAND;       if (jlo < 0) jlo = 0;
    int jhi = q0 + 31 + BAND;  if (jhi > T_SEQ - 1) jhi = T_SEQ - 1;
    for (int jt = (jlo >> 6); jt <= (jhi >> 6); ++jt) {
        const int j0 = jt << 6;
        __syncthreads();
        {   // stage K, V tiles
            const float* ks = Kb + (size_t)h*T_SEQ*DE + (size_t)j0*DE;
            const float* vs = Vb + (size_t)h*T_SEQ*DE + (size_t)j0*DE;
            #pragma unroll
            for (int rep = 0; rep < 4; ++rep) {
                int f = rep*256 + tid;
                int row = f >> 4, c4 = (f & 15) << 2;
                *(float4*)&Ks[row][c4] = *(const float4*)(ks + row*DE + c4);
                *(float4*)&Vs[row][c4] = *(const float4*)(vs + row*DE + c4);
            }
        }
        __syncthreads();

        // S = Q K^T  (rows tr*4+i, cols {tc, tc+32})
        float S[4][2];
        #pragma unroll
        for (int i = 0; i < 4; ++i) { S[i][0] = 0.f; S[i][1] = 0.f; }
        #pragma unroll
        for (int kk = 0; kk < DE; kk += 4) {
            float4 qv[4], kv[2];
            #pragma unroll
            for (int i = 0; i < 4; ++i) qv[i] = *(const float4*)&Qs[tr*4+i][kk];
            kv[0] = *(const float4*)&Ks[tc][kk];
            kv[1] = *(const float4*)&Ks[tc+32][kk];
            #pragma unroll
            for (int i = 0; i < 4; ++i) {
                S[i][0] += qv[i].x*kv[0].x + qv[i].y*kv[0].y + qv[i].z*kv[0].z + qv[i].w*kv[0].w;
                S[i][1] += qv[i].x*kv[1].x + qv[i].y*kv[1].y + qv[i].z*kv[1].z + qv[i].w*kv[1].w;
            }
        }

        // punish, exact-zero -> -2e20, online softmax update
        float alpha[4];
        #pragma unroll
        for (int i = 0; i < 4; ++i) {
            const int qg = q0 + tr*4 + i;
            float av[2];
            #pragma unroll
            for (int jj = 0; jj < 2; ++jj) {
                int jg = j0 + tc + jj*32;
                int delta = jg - qg;
                float s = S[i][jj] / scale;               // f32 division like numpy
                unsigned idx = (unsigned)(delta + BAND);
                double pdv = (idx < (unsigned)PD_N) ? pd[idx] : 0.0;
                double ad = (double)s * pdv;              // exact 24x24-bit product
                // RN32(s*punish)==0  <=>  |ad| <= 2^-150 (ties->0)
                av[jj] = (fabs(ad) <= 0x1p-150) ? -2e20f : (float)ad;
            }
            float mt = fmaxf(av[0], av[1]);
            #pragma unroll
            for (int off = 1; off <= 16; off <<= 1) mt = fmaxf(mt, __shfl_xor(mt, off));
            float mnew = fmaxf(m_i[i], mt);
            float al = expf(m_i[i] - mnew);               // 0 when old state was all-excluded
            float p0 = expf(av[0] - mnew);
            float p1 = expf(av[1] - mnew);
            float ps = p0 + p1;
            #pragma unroll
            for (int off = 1; off <= 16; off <<= 1) ps += __shfl_xor(ps, off);
            l_i[i] = l_i[i]*al + ps;
            m_i[i] = mnew;
            alpha[i] = al;
            Ps[tr*4+i][tc]      = p0;   // row group lives in one wave: no barrier
            Ps[tr*4+i][tc + 32] = p1;
        }

        // ctx = ctx*alpha + P V
        #pragma unroll
        for (int i = 0; i < 4; ++i) { cacc[i][0] *= alpha[i]; cacc[i][1] *= alpha[i]; }
        #pragma unroll
        for (int j4 = 0; j4 < DE; j4 += 4) {
            float4 pv[4];
            #pragma unroll
            for (int i = 0; i < 4; ++i) pv[i] = *(const float4*)&Ps[tr*4+i][j4];
            #pragma unroll
            for (int u = 0; u < 4; ++u) {
                float v0 = Vs[j4+u][tc];
                float v1 = Vs[j4+u][tc+32];
                #pragma unroll
                for (int i = 0; i < 4; ++i) {
                    float p = ((const float*)&pv[i])[u];
                    cacc[i][0] += p * v0;
                    cacc[i][1] += p * v1;
                }
            }
        }
    }

    #pragma unroll
    for (int i = 0; i < 4; ++i) {
        int q = q0 + tr*4 + i;
        float inv = 1.0f / l_i[i];
        float o0 = cacc[i][0] * inv;
        float o1 = cacc[i][1] * inv;
        if (q >= sl) { o0 = meanv[h*DE + tc]; o1 = meanv[h*DE + tc + 32]; }
        outbase[(size_t)q*DIM + tc]      = o0;
        outbase[(size_t)q*DIM + tc + 32] = o1;
    }
}

// ---------------- output projection + bias + residual -----------------------
__global__ __launch_bounds__(256) void proj_o_kernel(
    const float* __restrict__ ctx, const float* __restrict__ wo,
    const float* __restrict__ bo, const float* __restrict__ x,
    float* __restrict__ out)
{
    __shared__ float As[64][20];
    __shared__ float Ws[64][20];
    const int tid = threadIdx.x;
    const int m0 = blockIdx.x * 64;
    const int n0 = blockIdx.y * 64;
    float acc[4][4] = {};
    gemm64(ctx, wo, m0, n0, tid, acc, As, Ws);
    const int tr = tid >> 4, tc = tid & 15;
    #pragma unroll
    for (int i = 0; i < 4; ++i) {
        int m = m0 + tr + 16*i;
        #pragma unroll
        for (int j = 0; j < 4; ++j) {
            int n = n0 + tc + 16*j;
            out[(size_t)m*DIM + n] = acc[i][j] + bo[n] + x[(size_t)m*DIM + n];
        }
    }
}

extern "C" void kernel_launch(void* const* d_in, const int* in_sizes, int n_in,
                              void* d_out, int out_size, void* d_ws, size_t ws_size,
                              hipStream_t stream)
{
    (void)in_sizes; (void)n_in; (void)out_size;
    const float* x  = (const float*)d_in[0];
    const int*   sl = (const int*)d_in[1];
    const float* wq = (const float*)d_in[2];
    const float* bq = (const float*)d_in[3];
    const float* wk = (const float*)d_in[4];
    const float* bk = (const float*)d_in[5];
    const float* wv = (const float*)d_in[6];
    const float* bv = (const float*)d_in[7];
    const float* wo = (const float*)d_in[8];
    const float* bo = (const float*)d_in[9];
    const float* th = (const float*)d_in[10];
    float* out = (float*)d_out;

    // workspace layout: Q,K,V,CTX (16 MiB each) + meanV + punish table
    // requires ws_size >= ~64.1 MiB
    char* ws = (char*)d_ws;
    const size_t SZ = (size_t)NH * T_SEQ * DE * sizeof(float);
    float*  Qb = (float*)(ws);
    float*  Kb = (float*)(ws + SZ);
    float*  Vb = (float*)(ws + 2*SZ);
    float*  Cb = (float*)(ws + 3*SZ);
    float*  Mv = (float*)(ws + 4*SZ);
    double* Pd = (double*)(ws + 4*SZ + 65536);
    (void)ws_size;

    pd_kernel<<<dim3((PD_N + 255)/256), dim3(256), 0, stream>>>(Pd, th);
    proj_qkv_kernel<<<dim3(M_ROWS/64, DIM/64, 3), dim3(256), 0, stream>>>(
        x, wq, bq, wk, bk, wv, bv, sl, Qb, Kb, Vb);
    meanv_kernel<<<dim3(NH), dim3(256), 0, stream>>>(Vb, Mv);
    attn_kernel<<<dim3(T_SEQ/32, NH), dim3(256), 0, stream>>>(Qb, Kb, Vb, Pd, Mv, sl, Cb);
    proj_o_kernel<<<dim3(M_ROWS/64, DIM/64), dim3(256), 0, stream>>>(Cb, wo, bo, x, out);
}

// Round 2
// 344.386 us; speedup vs baseline: 3.0304x; 3.0304x over previous
//
#include <hip/hip_runtime.h>
#include <math.h>
#include <stdint.h>

#define B_SZ   8
#define T_SEQ  2048
#define DIM    256
#define NH     32            // B*E
#define DE     64
#define BAND   509           // |j-i|<=509 can have nonzero f32 punish (denormals)
#define PD_N   (2*BAND + 1)
#define M_ROWS (B_SZ * T_SEQ)

typedef __attribute__((ext_vector_type(8))) short short8;   // 8 bf16 (4 VGPRs)
typedef __attribute__((ext_vector_type(4))) float floatx4;  // MFMA C/D frag

__device__ __forceinline__ unsigned short f2bf(float x) {   // RNE f32->bf16
    unsigned u = __float_as_uint(x);
    u += 0x7fffu + ((u >> 16) & 1u);
    return (unsigned short)(u >> 16);
}
__device__ __forceinline__ float bf2f(unsigned short b) {
    return __uint_as_float(((unsigned)b) << 16);
}

// ---------------- punish table (f32-denormal-faithful, stored as double) -----
__global__ __launch_bounds__(256) void pd_kernel(double* __restrict__ pd,
                                                 const float* __restrict__ theta) {
    int i = blockIdx.x * 256 + threadIdx.x;
    if (i >= PD_N) return;
    float df  = (float)(i - BAND);
    float th  = theta[0];
    float arg = (-(df * df)) / (th * th);      // exact same f32 ops as numpy
    double pdd = exp((double)arg);
    double outv;
    if (pdd < 1.17549435082228751e-38) {
        outv = rint(pdd * 0x1p149) * 0x1p-149; // emulate f32 RNE into denormals
    } else {
        outv = (double)(float)pdd;
    }
    pd[i] = outv;
}

// ---------------- shared 64x64 fp32 GEMM core: acc = A[m,:] . W[n,:] --------
__device__ __forceinline__ void gemm64(const float* __restrict__ A,
                                       const float* __restrict__ W,
                                       int m0, int n0, int tid,
                                       float acc[4][4],
                                       float (*As)[20], float (*Ws)[20])
{
    const int srow = tid >> 2;
    const int scol = (tid & 3) << 2;
    const int tr = tid >> 4;
    const int tc = tid & 15;
    for (int k0 = 0; k0 < DIM; k0 += 16) {
        float4 av = *(const float4*)(A + (size_t)(m0 + srow) * DIM + k0 + scol);
        float4 wv = *(const float4*)(W + (size_t)(n0 + srow) * DIM + k0 + scol);
        __syncthreads();
        *(float4*)&As[srow][scol] = av;
        *(float4*)&Ws[srow][scol] = wv;
        __syncthreads();
        #pragma unroll
        for (int kk = 0; kk < 16; kk += 4) {
            float4 a[4], w[4];
            #pragma unroll
            for (int i = 0; i < 4; ++i) a[i] = *(const float4*)&As[tr + 16*i][kk];
            #pragma unroll
            for (int j = 0; j < 4; ++j) w[j] = *(const float4*)&Ws[tc + 16*j][kk];
            #pragma unroll
            for (int i = 0; i < 4; ++i)
                #pragma unroll
                for (int j = 0; j < 4; ++j)
                    acc[i][j] += a[i].x*w[j].x + a[i].y*w[j].y
                               + a[i].z*w[j].z + a[i].w*w[j].w;
        }
    }
}

// ---------------- QKV projection -> bf16 head layouts -----------------------
// head map: h=b*4+d/64, q=(d%64)*32+t/64, e=t%64
// Qh,Kh: [h][q][e] bf16 (masked q>=sl -> 0);  VT: [h][e][q] bf16 (unmasked)
__global__ __launch_bounds__(256) void proj_qkv_kernel(
    const float* __restrict__ x,
    const float* __restrict__ wq, const float* __restrict__ bq,
    const float* __restrict__ wk, const float* __restrict__ bk,
    const float* __restrict__ wv, const float* __restrict__ bv,
    const int* __restrict__ seq_len,
    unsigned short* __restrict__ Qh, unsigned short* __restrict__ Kh,
    unsigned short* __restrict__ VT)
{
    __shared__ float As[64][20];
    __shared__ float Ws[64][20];
    const int mode = blockIdx.z;                // 0:Q 1:K 2:V
    const float* W    = (mode == 0) ? wq : (mode == 1) ? wk : wv;
    const float* bias = (mode == 0) ? bq : (mode == 1) ? bk : bv;
    unsigned short* outp = (mode == 0) ? Qh : (mode == 1) ? Kh : VT;
    const int tid = threadIdx.x;
    const int m0 = blockIdx.x * 64;
    const int n0 = blockIdx.y * 64;
    float acc[4][4] = {};
    gemm64(x, W, m0, n0, tid, acc, As, Ws);
    const int tr = tid >> 4, tc = tid & 15;
    #pragma unroll
    for (int i = 0; i < 4; ++i) {
        int m  = m0 + tr + 16*i;
        int bb = m >> 11;
        int t  = m & (T_SEQ - 1);
        int sl = seq_len[bb];
        int e = t & 63, thi = t >> 6;
        #pragma unroll
        for (int j = 0; j < 4; ++j) {
            int n = n0 + tc + 16*j;
            int hh = bb*4 + (n >> 6);
            int q = (n & 63)*32 + thi;
            float v = acc[i][j] + bias[n];
            if (mode <= 1) {
                if (q >= sl) v = 0.0f;
                outp[(((size_t)hh*T_SEQ + q) << 6) + e] = f2bf(v);
            } else {
                outp[((size_t)hh*DE + e)*T_SEQ + q] = f2bf(v);
            }
        }
    }
}

// ---------------- per-head mean of V over attention axis (from VT) ----------
__global__ __launch_bounds__(256) void meanv_kernel(const unsigned short* __restrict__ VT,
                                                    float* __restrict__ mv) {
    __shared__ float red[256];
    int h = blockIdx.x, tid = threadIdx.x;
    int e = tid >> 2, seg = tid & 3;
    const unsigned short* p = VT + ((size_t)h*DE + e)*T_SEQ + seg*512;
    float s = 0.f;
    for (int i = 0; i < 512; i += 8) {
        uint4 u = *(const uint4*)(p + i);
        const unsigned short* w = (const unsigned short*)&u;
        #pragma unroll
        for (int k = 0; k < 8; ++k) s += bf2f(w[k]);
    }
    red[tid] = s;
    __syncthreads();
    if (seg == 0)
        mv[h*DE + e] = (red[tid] + red[tid+1] + red[tid+2] + red[tid+3]) * (1.0f/T_SEQ);
}

// ---------------- banded flash attention, bf16 MFMA, 64 q-rows/block --------
__global__ __launch_bounds__(256) void attn_mfma_kernel(
    const unsigned short* __restrict__ Qh, const unsigned short* __restrict__ Kh,
    const unsigned short* __restrict__ VT, const double* __restrict__ pdg,
    const float* __restrict__ meanv, const int* __restrict__ seq_len,
    float* __restrict__ ctxb)
{
    // stride 72 bf16 = 144 B = 36 banks -> b128 frag reads spread evenly
    __shared__ unsigned short Ks [64][72];
    __shared__ unsigned short VTs[64][72];
    __shared__ unsigned short Ps [4][16][72];  // per-wave P tile (C->A layout hop)
    __shared__ double pds[PD_N];

    const int tid  = threadIdx.x;
    const int wave = tid >> 6;
    const int lane = tid & 63;
    const int quad = lane >> 4;
    const int l15  = lane & 15;
    const int h  = blockIdx.y;
    const int b  = h >> 2;
    const int q0 = blockIdx.x * 64;
    const int sl = seq_len[b];
    float* outbase = ctxb + ((size_t)b*T_SEQ + q0)*DIM + (size_t)(h & 3)*64;

    if (q0 >= sl) {   // whole tile masked: softmax uniform over ALL 2048 -> meanV
        #pragma unroll
        for (int nt = 0; nt < 4; ++nt) {
            float mval = meanv[h*DE + l15 + 16*nt];
            #pragma unroll
            for (int r = 0; r < 4; ++r) {
                int row = wave*16 + quad*4 + r;
                outbase[(size_t)row*DIM + l15 + 16*nt] = mval;
            }
        }
        return;
    }

    for (int i = tid; i < PD_N; i += 256) pds[i] = pdg[i];

    // Q A-frags, loaded once (A[m=lane&15][k=quad*8+j])
    short8 qa0, qa1;
    {
        const unsigned short* qp = Qh + ((size_t)h*T_SEQ + q0 + wave*16 + l15)*DE + quad*8;
        qa0 = *(const short8*)(qp);
        qa1 = *(const short8*)(qp + 32);
    }

    float m_i[4], l_i[4];
    floatx4 cacc[4];
    #pragma unroll
    for (int r = 0; r < 4; ++r) { m_i[r] = -2e20f; l_i[r] = 0.f; }
    #pragma unroll
    for (int nt = 0; nt < 4; ++nt) cacc[nt] = (floatx4){0.f, 0.f, 0.f, 0.f};

    int jlo = q0 - BAND;      if (jlo < 0) jlo = 0;
    int jhi = q0 + 63 + BAND; if (jhi > T_SEQ - 1) jhi = T_SEQ - 1;
    const float RSC = 0.022097086912079612f;   // 1/sqrt(2048), mul ~ numpy's divide

    for (int jt = jlo >> 6; jt <= jhi >> 6; ++jt) {
        const int j0 = jt << 6;
        __syncthreads();
        {   // stage K tile and VT tile (16B/lane coalesced)
            const unsigned short* ksrc = Kh + ((size_t)h*T_SEQ + j0)*DE;
            const unsigned short* vsrc = VT + (size_t)h*DE*T_SEQ + j0;
            #pragma unroll
            for (int rnd = 0; rnd < 2; ++rnd) {
                int flat = rnd*256 + tid;
                int row = flat >> 3, c8 = (flat & 7)*8;
                *(uint4*)&Ks[row][c8]  = *(const uint4*)(ksrc + (size_t)row*DE + c8);
                *(uint4*)&VTs[row][c8] = *(const uint4*)(vsrc + (size_t)row*T_SEQ + c8);
            }
        }
        __syncthreads();

        // S = Q K^T : B[k][n] = K[n][k] -> row-contiguous reads of Ks
        floatx4 S[4];
        #pragma unroll
        for (int nt = 0; nt < 4; ++nt) {
            short8 kb0 = *(const short8*)&Ks[l15 + 16*nt][quad*8];
            short8 kb1 = *(const short8*)&Ks[l15 + 16*nt][32 + quad*8];
            floatx4 z = {0.f, 0.f, 0.f, 0.f};
            z = __builtin_amdgcn_mfma_f32_16x16x32_bf16(qa0, kb0, z, 0, 0, 0);
            z = __builtin_amdgcn_mfma_f32_16x16x32_bf16(qa1, kb1, z, 0, 0, 0);
            S[nt] = z;
        }

        // punish + exact-zero exclusion (f64, bit-faithful to numpy RN32)
        float av[4][4];
        #pragma unroll
        for (int nt = 0; nt < 4; ++nt) {
            int jg = j0 + l15 + 16*nt;
            #pragma unroll
            for (int r = 0; r < 4; ++r) {
                int qg = q0 + wave*16 + quad*4 + r;
                float s = S[nt][r] * RSC;
                int idx = jg - qg + BAND;
                double pdv = ((unsigned)idx < (unsigned)PD_N) ? pds[idx] : 0.0;
                double ad = (double)s * pdv;              // 24x24-bit: exact
                av[nt][r] = (fabs(ad) <= 0x1p-150) ? -2e20f : (float)ad;
            }
        }

        // online softmax (rows live in 16-lane groups; C-layout row=quad*4+r)
        float alpha[4];
        #pragma unroll
        for (int r = 0; r < 4; ++r) {
            float mt = fmaxf(fmaxf(av[0][r], av[1][r]), fmaxf(av[2][r], av[3][r]));
            #pragma unroll
            for (int off = 1; off <= 8; off <<= 1) mt = fmaxf(mt, __shfl_xor(mt, off));
            float mnew = fmaxf(m_i[r], mt);
            alpha[r] = __expf(m_i[r] - mnew);   // 0 once real entries seen (wipes -2e20 garbage)
            float p0 = __expf(av[0][r] - mnew);
            float p1 = __expf(av[1][r] - mnew);
            float p2 = __expf(av[2][r] - mnew);
            float p3 = __expf(av[3][r] - mnew);
            float ps = (p0 + p1) + (p2 + p3);
            #pragma unroll
            for (int off = 1; off <= 8; off <<= 1) ps += __shfl_xor(ps, off);
            l_i[r] = l_i[r]*alpha[r] + ps;
            m_i[r] = mnew;
            Ps[wave][quad*4+r][l15]      = f2bf(p0);
            Ps[wave][quad*4+r][l15+16]   = f2bf(p1);
            Ps[wave][quad*4+r][l15+32]   = f2bf(p2);
            Ps[wave][quad*4+r][l15+48]   = f2bf(p3);
        }

        // PV: A = P (LDS round-trip to A-layout), B[k][n] = V[j0+k][n] = VTs[n][k]
        short8 pa0 = *(const short8*)&Ps[wave][l15][quad*8];
        short8 pa1 = *(const short8*)&Ps[wave][l15][32 + quad*8];
        #pragma unroll
        for (int nt = 0; nt < 4; ++nt) {
            short8 vb0 = *(const short8*)&VTs[l15 + 16*nt][quad*8];
            short8 vb1 = *(const short8*)&VTs[l15 + 16*nt][32 + quad*8];
            floatx4 c = cacc[nt];
            #pragma unroll
            for (int r = 0; r < 4; ++r) c[r] *= alpha[r];
            c = __builtin_amdgcn_mfma_f32_16x16x32_bf16(pa0, vb0, c, 0, 0, 0);
            c = __builtin_amdgcn_mfma_f32_16x16x32_bf16(pa1, vb1, c, 0, 0, 0);
            cacc[nt] = c;
        }
    }

    #pragma unroll
    for (int r = 0; r < 4; ++r) l_i[r] = 1.0f / l_i[r];
    #pragma unroll
    for (int nt = 0; nt < 4; ++nt) {
        #pragma unroll
        for (int r = 0; r < 4; ++r) {
            int row = wave*16 + quad*4 + r;
            int qg = q0 + row;
            float o = cacc[nt][r] * l_i[r];
            if (qg >= sl) o = meanv[h*DE + l15 + 16*nt];
            outbase[(size_t)row*DIM + l15 + 16*nt] = o;
        }
    }
}

// ---------------- output projection + bias + residual -----------------------
__global__ __launch_bounds__(256) void proj_o_kernel(
    const float* __restrict__ ctx, const float* __restrict__ wo,
    const float* __restrict__ bo, const float* __restrict__ x,
    float* __restrict__ out)
{
    __shared__ float As[64][20];
    __shared__ float Ws[64][20];
    const int tid = threadIdx.x;
    const int m0 = blockIdx.x * 64;
    const int n0 = blockIdx.y * 64;
    float acc[4][4] = {};
    gemm64(ctx, wo, m0, n0, tid, acc, As, Ws);
    const int tr = tid >> 4, tc = tid & 15;
    #pragma unroll
    for (int i = 0; i < 4; ++i) {
        int m = m0 + tr + 16*i;
        #pragma unroll
        for (int j = 0; j < 4; ++j) {
            int n = n0 + tc + 16*j;
            out[(size_t)m*DIM + n] = acc[i][j] + bo[n] + x[(size_t)m*DIM + n];
        }
    }
}

extern "C" void kernel_launch(void* const* d_in, const int* in_sizes, int n_in,
                              void* d_out, int out_size, void* d_ws, size_t ws_size,
                              hipStream_t stream)
{
    (void)in_sizes; (void)n_in; (void)out_size; (void)ws_size;
    const float* x  = (const float*)d_in[0];
    const int*   sl = (const int*)d_in[1];
    const float* wq = (const float*)d_in[2];
    const float* bq = (const float*)d_in[3];
    const float* wk = (const float*)d_in[4];
    const float* bk = (const float*)d_in[5];
    const float* wv = (const float*)d_in[6];
    const float* bv = (const float*)d_in[7];
    const float* wo = (const float*)d_in[8];
    const float* bo = (const float*)d_in[9];
    const float* th = (const float*)d_in[10];
    float* out = (float*)d_out;

    // workspace: Qh/Kh/VT bf16 (8 MiB each) + ctx f32 (16 MiB) + meanV + pd
    char* ws = (char*)d_ws;
    const size_t SZH = (size_t)NH * T_SEQ * DE * sizeof(unsigned short);  // 8 MiB
    const size_t SZC = (size_t)M_ROWS * DIM * sizeof(float);              // 16 MiB
    unsigned short* Qh = (unsigned short*)(ws);
    unsigned short* Kh = (unsigned short*)(ws + SZH);
    unsigned short* VT = (unsigned short*)(ws + 2*SZH);
    float*  Cb = (float*)(ws + 3*SZH);
    float*  Mv = (float*)(ws + 3*SZH + SZC);
    double* Pd = (double*)(ws + 3*SZH + SZC + 65536);

    pd_kernel<<<dim3((PD_N + 255)/256), dim3(256), 0, stream>>>(Pd, th);
    proj_qkv_kernel<<<dim3(M_ROWS/64, DIM/64, 3), dim3(256), 0, stream>>>(
        x, wq, bq, wk, bk, wv, bv, sl, Qh, Kh, VT);
    meanv_kernel<<<dim3(NH), dim3(256), 0, stream>>>(VT, Mv);
    attn_mfma_kernel<<<dim3(T_SEQ/64, NH), dim3(256), 0, stream>>>(Qh, Kh, VT, Pd, Mv, sl, Cb);
    proj_o_kernel<<<dim3(M_ROWS/64, DIM/64), dim3(256), 0, stream>>>(Cb, wo, bo, x, out);
}

// Round 3
// 239.891 us; speedup vs baseline: 4.3505x; 1.4356x over previous
//
#include <hip/hip_runtime.h>
#include <math.h>
#include <stdint.h>

#define B_SZ   8
#define T_SEQ  2048
#define DIM    256
#define NH     32            // B*E
#define DE     64
#define BAND   509           // |j-i|<=509 can have nonzero f32 punish (denormals)
#define PD_N   (2*BAND + 1)
#define M_ROWS (B_SZ * T_SEQ)

typedef __attribute__((ext_vector_type(8))) short short8;   // 8 bf16 (4 VGPRs)
typedef __attribute__((ext_vector_type(4))) float floatx4;  // MFMA C/D frag
typedef unsigned short ushort_t;

__device__ __forceinline__ ushort_t f2bf(float x) {   // RNE f32->bf16
    unsigned u = __float_as_uint(x);
    u += 0x7fffu + ((u >> 16) & 1u);
    return (ushort_t)(u >> 16);
}
__device__ __forceinline__ float bf2f(ushort_t b) {
    return __uint_as_float(((unsigned)b) << 16);
}
__device__ __forceinline__ unsigned pack2(float a, float b) {
    return (unsigned)f2bf(a) | ((unsigned)f2bf(b) << 16);
}

// ============ prep: x,w -> bf16; pd table (f32-denormal-faithful) ===========
// grid: [0,2048) x-chunks, [2048,2176) w-chunks, [2176,2180) pd
__global__ __launch_bounds__(256) void prep_kernel(
    const float* __restrict__ x,
    const float* __restrict__ wq, const float* __restrict__ wk,
    const float* __restrict__ wv, const float* __restrict__ wo,
    const float* __restrict__ theta,
    ushort_t* __restrict__ xb, ushort_t* __restrict__ wb,
    double* __restrict__ pd)
{
    const int bid = blockIdx.x, tid = threadIdx.x;
    if (bid < 2048) {
        size_t i8 = ((size_t)bid * 256 + tid) * 8;
        float4 a = *(const float4*)(x + i8);
        float4 b = *(const float4*)(x + i8 + 4);
        uint4 o;
        o.x = pack2(a.x, a.y); o.y = pack2(a.z, a.w);
        o.z = pack2(b.x, b.y); o.w = pack2(b.z, b.w);
        *(uint4*)(xb + i8) = o;
    } else if (bid < 2176) {
        size_t w8 = ((size_t)(bid - 2048) * 256 + tid) * 8;
        int which = (int)(w8 >> 16);
        const float* src = (which == 0) ? wq : (which == 1) ? wk : (which == 2) ? wv : wo;
        size_t off = w8 & 65535;
        float4 a = *(const float4*)(src + off);
        float4 b = *(const float4*)(src + off + 4);
        uint4 o;
        o.x = pack2(a.x, a.y); o.y = pack2(a.z, a.w);
        o.z = pack2(b.x, b.y); o.w = pack2(b.z, b.w);
        *(uint4*)(wb + w8) = o;
    } else {
        int i = (bid - 2176) * 256 + tid;
        if (i >= PD_N) return;
        float df  = (float)(i - BAND);
        float th  = theta[0];
        float arg = (-(df * df)) / (th * th);      // exact same f32 ops as numpy
        double pdd = exp((double)arg);
        double outv;
        if (pdd < 1.17549435082228751e-38) {
            outv = rint(pdd * 0x1p149) * 0x1p-149; // f32 RNE into denormal range
        } else {
            outv = (double)(float)pdd;
        }
        pd[i] = outv;
    }
}

// ============ QKV projection: zero-LDS MFMA GEMM ============================
// task = (n-tile64 of 768, m-strip of 64 rows); B-frags register-resident.
// head map: h=b*4+d/64, q=(d%64)*32+t/64, e=t%64.  Qh/Kh masked q>=sl -> 0.
__global__ __launch_bounds__(256, 2) void proj_qkv_mfma(
    const ushort_t* __restrict__ xb, const ushort_t* __restrict__ wb,
    const float* __restrict__ bq, const float* __restrict__ bk,
    const float* __restrict__ bv, const int* __restrict__ seq_len,
    ushort_t* __restrict__ Qh, ushort_t* __restrict__ Kh, ushort_t* __restrict__ Vh)
{
    const int wave = threadIdx.x >> 6, lane = threadIdx.x & 63;
    const int quad = lane >> 4, l15 = lane & 15;
    const int task = blockIdx.x * 4 + wave;      // 3072 tasks
    const int nt64 = task % 12;
    const int mstrip = task / 12;
    const int mode = nt64 >> 2;                  // 0:Q 1:K 2:V
    const int nloc_base = (nt64 & 3) * 64;       // d within [0,256)
    const ushort_t* Wp = wb + (size_t)mode * 65536;
    const int m0 = mstrip * 64;
    const int bb = m0 >> 11;
    const int th0 = (m0 >> 6) & 31;
    const int sl = seq_len[bb];
    ushort_t* outp = (mode == 0) ? Qh : (mode == 1) ? Kh : Vh;
    const float* bias = (mode == 0) ? bq : (mode == 1) ? bk : bv;
    const int hh = bb * 4 + (nloc_base >> 6);

    short8 Bf[4][8];
    #pragma unroll
    for (int nt = 0; nt < 4; ++nt) {
        int nrow = nloc_base + nt * 16 + l15;
        #pragma unroll
        for (int ks = 0; ks < 8; ++ks)
            Bf[nt][ks] = *(const short8*)(Wp + (size_t)nrow * 256 + ks * 32 + quad * 8);
    }
    float bias4[4]; int qv[4];
    #pragma unroll
    for (int nt = 0; nt < 4; ++nt) {
        int dl = nloc_base + nt * 16 + l15;
        bias4[nt] = bias[dl];
        qv[nt] = (dl & 63) * 32 + th0;
    }

    for (int mb = 0; mb < 4; ++mb) {
        const int mb0 = m0 + mb * 16;
        short8 Af[8];
        #pragma unroll
        for (int ks = 0; ks < 8; ++ks)
            Af[ks] = *(const short8*)(xb + (size_t)(mb0 + l15) * 256 + ks * 32 + quad * 8);
        floatx4 acc[4];
        #pragma unroll
        for (int nt = 0; nt < 4; ++nt) acc[nt] = (floatx4){0.f, 0.f, 0.f, 0.f};
        #pragma unroll
        for (int ks = 0; ks < 8; ++ks)
            #pragma unroll
            for (int nt = 0; nt < 4; ++nt)
                acc[nt] = __builtin_amdgcn_mfma_f32_16x16x32_bf16(Af[ks], Bf[nt][ks], acc[nt], 0, 0, 0);
        const int e_base = (mb0 & 63) + quad * 4;
        #pragma unroll
        for (int nt = 0; nt < 4; ++nt) {
            bool msk = (mode <= 1) && (qv[nt] >= sl);
            float v0 = msk ? 0.f : acc[nt][0] + bias4[nt];
            float v1 = msk ? 0.f : acc[nt][1] + bias4[nt];
            float v2 = msk ? 0.f : acc[nt][2] + bias4[nt];
            float v3 = msk ? 0.f : acc[nt][3] + bias4[nt];
            uint2 pk; pk.x = pack2(v0, v1); pk.y = pack2(v2, v3);
            *(uint2*)(outp + (((size_t)hh * T_SEQ + qv[nt]) << 6) + e_base) = pk;
        }
    }
}

// ============ per-head mean of V over attention axis (from Vh) ==============
__global__ __launch_bounds__(256) void meanv_kernel(const ushort_t* __restrict__ Vh,
                                                    float* __restrict__ mv) {
    __shared__ float red[256];
    const int h = blockIdx.x, tid = threadIdx.x;
    const int e = tid & 63, strip = tid >> 6;
    const ushort_t* p = Vh + ((size_t)h * T_SEQ + strip * 512) * DE + e;
    float s = 0.f;
    for (int q = 0; q < 512; ++q) s += bf2f(p[(size_t)q * DE]);
    red[tid] = s;
    __syncthreads();
    if (strip == 0)
        mv[h * DE + e] = (red[e] + red[64 + e] + red[128 + e] + red[192 + e]) * (1.0f / T_SEQ);
}

// ============ banded flash attention, bf16 MFMA, 64 q-rows/block ============
__global__ __launch_bounds__(256) void attn_mfma_kernel(
    const ushort_t* __restrict__ Qh, const ushort_t* __restrict__ Kh,
    const ushort_t* __restrict__ Vh, const double* __restrict__ pdg,
    const float* __restrict__ meanv, const int* __restrict__ seq_len,
    ushort_t* __restrict__ ctxb)
{
    __shared__ ushort_t Ks [64][72];   // [j][e]
    __shared__ ushort_t VTs[64][72];   // [e][j]  (transposed at staging)
    __shared__ ushort_t Ps [4][16][72];
    __shared__ double pds[PD_N];

    const int tid  = threadIdx.x;
    const int wave = tid >> 6;
    const int lane = tid & 63;
    const int quad = lane >> 4;
    const int l15  = lane & 15;
    const int h  = blockIdx.y;
    const int b  = h >> 2;
    const int q0 = blockIdx.x * 64;
    const int sl = seq_len[b];
    ushort_t* outbase = ctxb + ((size_t)b * T_SEQ + q0) * DIM + (size_t)(h & 3) * 64;

    if (q0 >= sl) {   // whole tile masked: softmax uniform over ALL 2048 -> meanV
        #pragma unroll
        for (int nt = 0; nt < 4; ++nt) {
            ushort_t mval = f2bf(meanv[h * DE + l15 + 16 * nt]);
            #pragma unroll
            for (int r = 0; r < 4; ++r) {
                int row = wave * 16 + quad * 4 + r;
                outbase[(size_t)row * DIM + l15 + 16 * nt] = mval;
            }
        }
        return;
    }

    for (int i = tid; i < PD_N; i += 256) pds[i] = pdg[i];

    short8 qa0, qa1;
    {
        const ushort_t* qp = Qh + ((size_t)h * T_SEQ + q0 + wave * 16 + l15) * DE + quad * 8;
        qa0 = *(const short8*)(qp);
        qa1 = *(const short8*)(qp + 32);
    }

    float m_i[4], l_i[4];
    floatx4 cacc[4];
    #pragma unroll
    for (int r = 0; r < 4; ++r) { m_i[r] = -2e20f; l_i[r] = 0.f; }
    #pragma unroll
    for (int nt = 0; nt < 4; ++nt) cacc[nt] = (floatx4){0.f, 0.f, 0.f, 0.f};

    int jlo = q0 - BAND;      if (jlo < 0) jlo = 0;
    int jhi = q0 + 63 + BAND; if (jhi > T_SEQ - 1) jhi = T_SEQ - 1;
    const float RSC = 0.022097086912079612f;   // 1/sqrt(2048)

    for (int jt = jlo >> 6; jt <= jhi >> 6; ++jt) {
        const int j0 = jt << 6;
        __syncthreads();
        {   // stage K (vector) and V (transposed, scalar b16 writes)
            const ushort_t* ksrc = Kh + ((size_t)h * T_SEQ + j0) * DE;
            const ushort_t* vsrc = Vh + ((size_t)h * T_SEQ + j0) * DE;
            #pragma unroll
            for (int rnd = 0; rnd < 2; ++rnd) {
                int flat = rnd * 256 + tid;
                int row = flat >> 3, c8 = (flat & 7) * 8;
                *(uint4*)&Ks[row][c8] = *(const uint4*)(ksrc + (size_t)row * DE + c8);
            }
            union { uint4 u4[2]; ushort_t us[16]; } vv;
            vv.u4[0] = *(const uint4*)(vsrc + (size_t)lane * DE + wave * 16);
            vv.u4[1] = *(const uint4*)(vsrc + (size_t)lane * DE + wave * 16 + 8);
            #pragma unroll
            for (int k = 0; k < 16; ++k) VTs[wave * 16 + k][lane] = vv.us[k];
        }
        __syncthreads();

        // S = Q K^T
        floatx4 S[4];
        #pragma unroll
        for (int nt = 0; nt < 4; ++nt) {
            short8 kb0 = *(const short8*)&Ks[l15 + 16 * nt][quad * 8];
            short8 kb1 = *(const short8*)&Ks[l15 + 16 * nt][32 + quad * 8];
            floatx4 z = {0.f, 0.f, 0.f, 0.f};
            z = __builtin_amdgcn_mfma_f32_16x16x32_bf16(qa0, kb0, z, 0, 0, 0);
            z = __builtin_amdgcn_mfma_f32_16x16x32_bf16(qa1, kb1, z, 0, 0, 0);
            S[nt] = z;
        }

        // punish + exact-zero exclusion (f64, bit-faithful to numpy RN32)
        float av[4][4];
        #pragma unroll
        for (int nt = 0; nt < 4; ++nt) {
            int jg = j0 + l15 + 16 * nt;
            #pragma unroll
            for (int r = 0; r < 4; ++r) {
                int qg = q0 + wave * 16 + quad * 4 + r;
                float s = S[nt][r] * RSC;
                int idx = jg - qg + BAND;
                double pdv = ((unsigned)idx < (unsigned)PD_N) ? pds[idx] : 0.0;
                double ad = (double)s * pdv;              // 24x24-bit: exact
                av[nt][r] = (fabs(ad) <= 0x1p-150) ? -2e20f : (float)ad;
            }
        }

        // online softmax (rows live in 16-lane groups)
        float alpha[4];
        #pragma unroll
        for (int r = 0; r < 4; ++r) {
            float mt = fmaxf(fmaxf(av[0][r], av[1][r]), fmaxf(av[2][r], av[3][r]));
            #pragma unroll
            for (int off = 1; off <= 8; off <<= 1) mt = fmaxf(mt, __shfl_xor(mt, off));
            float mnew = fmaxf(m_i[r], mt);
            alpha[r] = __expf(m_i[r] - mnew);
            float p0 = __expf(av[0][r] - mnew);
            float p1 = __expf(av[1][r] - mnew);
            float p2 = __expf(av[2][r] - mnew);
            float p3 = __expf(av[3][r] - mnew);
            float ps = (p0 + p1) + (p2 + p3);
            #pragma unroll
            for (int off = 1; off <= 8; off <<= 1) ps += __shfl_xor(ps, off);
            l_i[r] = l_i[r] * alpha[r] + ps;
            m_i[r] = mnew;
            Ps[wave][quad * 4 + r][l15]      = f2bf(p0);
            Ps[wave][quad * 4 + r][l15 + 16] = f2bf(p1);
            Ps[wave][quad * 4 + r][l15 + 32] = f2bf(p2);
            Ps[wave][quad * 4 + r][l15 + 48] = f2bf(p3);
        }

        // PV
        short8 pa0 = *(const short8*)&Ps[wave][l15][quad * 8];
        short8 pa1 = *(const short8*)&Ps[wave][l15][32 + quad * 8];
        #pragma unroll
        for (int nt = 0; nt < 4; ++nt) {
            short8 vb0 = *(const short8*)&VTs[l15 + 16 * nt][quad * 8];
            short8 vb1 = *(const short8*)&VTs[l15 + 16 * nt][32 + quad * 8];
            floatx4 c = cacc[nt];
            #pragma unroll
            for (int r = 0; r < 4; ++r) c[r] *= alpha[r];
            c = __builtin_amdgcn_mfma_f32_16x16x32_bf16(pa0, vb0, c, 0, 0, 0);
            c = __builtin_amdgcn_mfma_f32_16x16x32_bf16(pa1, vb1, c, 0, 0, 0);
            cacc[nt] = c;
        }
    }

    #pragma unroll
    for (int r = 0; r < 4; ++r) l_i[r] = 1.0f / l_i[r];
    #pragma unroll
    for (int nt = 0; nt < 4; ++nt) {
        #pragma unroll
        for (int r = 0; r < 4; ++r) {
            int row = wave * 16 + quad * 4 + r;
            int qg = q0 + row;
            float o = cacc[nt][r] * l_i[r];
            if (qg >= sl) o = meanv[h * DE + l15 + 16 * nt];
            outbase[(size_t)row * DIM + l15 + 16 * nt] = f2bf(o);
        }
    }
}

// ============ output projection + bias + residual (zero-LDS MFMA) ===========
__global__ __launch_bounds__(256, 2) void proj_o_mfma(
    const ushort_t* __restrict__ ctx, const ushort_t* __restrict__ wb,
    const float* __restrict__ bo, const float* __restrict__ x,
    float* __restrict__ out)
{
    const int wave = threadIdx.x >> 6, lane = threadIdx.x & 63;
    const int quad = lane >> 4, l15 = lane & 15;
    const int task = blockIdx.x * 4 + wave;      // 1024 tasks
    const int nt64 = task & 3;
    const int mstrip = task >> 2;
    const int n0 = nt64 * 64;
    const ushort_t* Wp = wb + (size_t)3 * 65536; // wo
    const int m0 = mstrip * 64;

    short8 Bf[4][8];
    #pragma unroll
    for (int nt = 0; nt < 4; ++nt) {
        int nrow = n0 + nt * 16 + l15;
        #pragma unroll
        for (int ks = 0; ks < 8; ++ks)
            Bf[nt][ks] = *(const short8*)(Wp + (size_t)nrow * 256 + ks * 32 + quad * 8);
    }
    float bias4[4];
    #pragma unroll
    for (int nt = 0; nt < 4; ++nt) bias4[nt] = bo[n0 + nt * 16 + l15];

    for (int mb = 0; mb < 4; ++mb) {
        const int mb0 = m0 + mb * 16;
        short8 Af[8];
        #pragma unroll
        for (int ks = 0; ks < 8; ++ks)
            Af[ks] = *(const short8*)(ctx + (size_t)(mb0 + l15) * 256 + ks * 32 + quad * 8);
        floatx4 acc[4];
        #pragma unroll
        for (int nt = 0; nt < 4; ++nt) acc[nt] = (floatx4){0.f, 0.f, 0.f, 0.f};
        #pragma unroll
        for (int ks = 0; ks < 8; ++ks)
            #pragma unroll
            for (int nt = 0; nt < 4; ++nt)
                acc[nt] = __builtin_amdgcn_mfma_f32_16x16x32_bf16(Af[ks], Bf[nt][ks], acc[nt], 0, 0, 0);
        #pragma unroll
        for (int nt = 0; nt < 4; ++nt) {
            int d = n0 + nt * 16 + l15;
            #pragma unroll
            for (int r = 0; r < 4; ++r) {
                size_t mi = (size_t)(mb0 + quad * 4 + r) * 256 + d;
                out[mi] = acc[nt][r] + bias4[nt] + x[mi];
            }
        }
    }
}

extern "C" void kernel_launch(void* const* d_in, const int* in_sizes, int n_in,
                              void* d_out, int out_size, void* d_ws, size_t ws_size,
                              hipStream_t stream)
{
    (void)in_sizes; (void)n_in; (void)out_size; (void)ws_size;
    const float* x  = (const float*)d_in[0];
    const int*   sl = (const int*)d_in[1];
    const float* wq = (const float*)d_in[2];
    const float* bq = (const float*)d_in[3];
    const float* wk = (const float*)d_in[4];
    const float* bk = (const float*)d_in[5];
    const float* wv = (const float*)d_in[6];
    const float* bv = (const float*)d_in[7];
    const float* wo = (const float*)d_in[8];
    const float* bo = (const float*)d_in[9];
    const float* th = (const float*)d_in[10];
    float* out = (float*)d_out;

    char* ws = (char*)d_ws;
    const size_t SZH = (size_t)M_ROWS * DIM * sizeof(ushort_t);  // 8 MiB
    ushort_t* xb = (ushort_t*)(ws);
    ushort_t* wb = (ushort_t*)(ws + SZH);                        // 512 KiB
    ushort_t* Qh = (ushort_t*)(ws + SZH + 524288);
    ushort_t* Kh = (ushort_t*)(ws + 2*SZH + 524288);
    ushort_t* Vh = (ushort_t*)(ws + 3*SZH + 524288);
    ushort_t* Cb = (ushort_t*)(ws + 4*SZH + 524288);
    float*    Mv = (float*)   (ws + 5*SZH + 524288);
    double*   Pd = (double*)  (ws + 5*SZH + 524288 + 8192);

    prep_kernel<<<dim3(2180), dim3(256), 0, stream>>>(x, wq, wk, wv, wo, th, xb, wb, Pd);
    proj_qkv_mfma<<<dim3(768), dim3(256), 0, stream>>>(xb, wb, bq, bk, bv, sl, Qh, Kh, Vh);
    meanv_kernel<<<dim3(NH), dim3(256), 0, stream>>>(Vh, Mv);
    attn_mfma_kernel<<<dim3(T_SEQ/64, NH), dim3(256), 0, stream>>>(Qh, Kh, Vh, Pd, Mv, sl, Cb);
    proj_o_mfma<<<dim3(256), dim3(256), 0, stream>>>(Cb, wb, bo, x, out);
}

// Round 4
// 198.267 us; speedup vs baseline: 5.2638x; 1.2099x over previous
//
#include <hip/hip_runtime.h>
#include <math.h>
#include <stdint.h>

#define B_SZ   8
#define T_SEQ  2048
#define DIM    256
#define NH     32            // B*E
#define DE     64
#define BAND   509           // |j-i|<=509 can have nonzero f32 punish (denormals)
#define THR_N  577           // thr table indexed by |delta| 0..576
#define M_ROWS (B_SZ * T_SEQ)

typedef __attribute__((ext_vector_type(8))) short short8;   // 8 bf16 (4 VGPRs)
typedef __attribute__((ext_vector_type(4))) float floatx4;  // MFMA C/D frag
typedef unsigned short ushort_t;

__device__ __forceinline__ ushort_t f2bf(float x) {   // RNE f32->bf16
    unsigned u = __float_as_uint(x);
    u += 0x7fffu + ((u >> 16) & 1u);
    return (ushort_t)(u >> 16);
}
__device__ __forceinline__ float bf2f(ushort_t b) {
    return __uint_as_float(((unsigned)b) << 16);
}
__device__ __forceinline__ unsigned pack2(float a, float b) {
    return (unsigned)f2bf(a) | ((unsigned)f2bf(b) << 16);
}

// ============ prep: x,w -> bf16; thr table (f32-denormal-faithful) ==========
// grid: [0,2048) x-chunks, [2048,2176) w-chunks, [2176,2179) thr
__global__ __launch_bounds__(256) void prep_kernel(
    const float* __restrict__ x,
    const float* __restrict__ wq, const float* __restrict__ wk,
    const float* __restrict__ wv, const float* __restrict__ wo,
    const float* __restrict__ theta,
    ushort_t* __restrict__ xb, ushort_t* __restrict__ wb,
    float* __restrict__ thr_g)
{
    const int bid = blockIdx.x, tid = threadIdx.x;
    if (bid < 2048) {
        size_t i8 = ((size_t)bid * 256 + tid) * 8;
        float4 a = *(const float4*)(x + i8);
        float4 b = *(const float4*)(x + i8 + 4);
        uint4 o;
        o.x = pack2(a.x, a.y); o.y = pack2(a.z, a.w);
        o.z = pack2(b.x, b.y); o.w = pack2(b.z, b.w);
        *(uint4*)(xb + i8) = o;
    } else if (bid < 2176) {
        size_t w8 = ((size_t)(bid - 2048) * 256 + tid) * 8;
        int which = (int)(w8 >> 16);
        const float* src = (which == 0) ? wq : (which == 1) ? wk : (which == 2) ? wv : wo;
        size_t off = w8 & 65535;
        float4 a = *(const float4*)(src + off);
        float4 b = *(const float4*)(src + off + 4);
        uint4 o;
        o.x = pack2(a.x, a.y); o.y = pack2(a.z, a.w);
        o.z = pack2(b.x, b.y); o.w = pack2(b.z, b.w);
        *(uint4*)(wb + w8) = o;
    } else {
        int i = (bid - 2176) * 256 + tid;
        if (i >= THR_N) return;
        float df  = (float)i;
        float th  = theta[0];
        float arg = (-(df * df)) / (th * th);      // exact same f32 ops as numpy
        double pdd = exp((double)arg);
        double outv;                               // f32-RNE value incl. denormals
        if (pdd < 1.17549435082228751e-38) {
            outv = rint(pdd * 0x1p149) * 0x1p-149;
        } else {
            outv = (double)(float)pdd;
        }
        // exclusion: RN32(s*pd)==0  <=>  |s| <= 2^-150/pd
        float thr = (outv == 0.0) ? __builtin_inff() : (float)(0x1p-150 / outv);
        thr_g[i] = thr;
    }
}

// ============ QKV projection: zero-LDS MFMA GEMM (Q pre-scaled 1/sqrt(T)) ===
// head map: h=b*4+d/64, q=(d%64)*32+t/64, e=t%64.  Qh/Kh masked q>=sl -> 0.
__global__ __launch_bounds__(256, 2) void proj_qkv_mfma(
    const ushort_t* __restrict__ xb, const ushort_t* __restrict__ wb,
    const float* __restrict__ bq, const float* __restrict__ bk,
    const float* __restrict__ bv, const int* __restrict__ seq_len,
    ushort_t* __restrict__ Qh, ushort_t* __restrict__ Kh, ushort_t* __restrict__ Vh)
{
    const int wave = threadIdx.x >> 6, lane = threadIdx.x & 63;
    const int quad = lane >> 4, l15 = lane & 15;
    const int task = blockIdx.x * 4 + wave;      // 3072 tasks
    const int nt64 = task % 12;
    const int mstrip = task / 12;
    const int mode = nt64 >> 2;                  // 0:Q 1:K 2:V
    const int nloc_base = (nt64 & 3) * 64;       // d within [0,256)
    const ushort_t* Wp = wb + (size_t)mode * 65536;
    const int m0 = mstrip * 64;
    const int bb = m0 >> 11;
    const int th0 = (m0 >> 6) & 31;
    const int sl = seq_len[bb];
    ushort_t* outp = (mode == 0) ? Qh : (mode == 1) ? Kh : Vh;
    const float* bias = (mode == 0) ? bq : (mode == 1) ? bk : bv;
    const int hh = bb * 4 + (nloc_base >> 6);
    const float oscale = (mode == 0) ? 0.022097086912079612f : 1.0f;  // 1/sqrt(2048)

    short8 Bf[4][8];
    #pragma unroll
    for (int nt = 0; nt < 4; ++nt) {
        int nrow = nloc_base + nt * 16 + l15;
        #pragma unroll
        for (int ks = 0; ks < 8; ++ks)
            Bf[nt][ks] = *(const short8*)(Wp + (size_t)nrow * 256 + ks * 32 + quad * 8);
    }
    float bias4[4]; int qv[4];
    #pragma unroll
    for (int nt = 0; nt < 4; ++nt) {
        int dl = nloc_base + nt * 16 + l15;
        bias4[nt] = bias[dl];
        qv[nt] = (dl & 63) * 32 + th0;
    }

    short8 Acur[8];
    #pragma unroll
    for (int ks = 0; ks < 8; ++ks)
        Acur[ks] = *(const short8*)(xb + (size_t)(m0 + l15) * 256 + ks * 32 + quad * 8);

    #pragma unroll
    for (int mb = 0; mb < 4; ++mb) {
        const int mb0 = m0 + mb * 16;
        short8 Anext[8];
        if (mb < 3) {
            #pragma unroll
            for (int ks = 0; ks < 8; ++ks)
                Anext[ks] = *(const short8*)(xb + (size_t)(mb0 + 16 + l15) * 256 + ks * 32 + quad * 8);
        }
        floatx4 acc[4];
        #pragma unroll
        for (int nt = 0; nt < 4; ++nt) acc[nt] = (floatx4){0.f, 0.f, 0.f, 0.f};
        #pragma unroll
        for (int ks = 0; ks < 8; ++ks)
            #pragma unroll
            for (int nt = 0; nt < 4; ++nt)
                acc[nt] = __builtin_amdgcn_mfma_f32_16x16x32_bf16(Acur[ks], Bf[nt][ks], acc[nt], 0, 0, 0);
        const int e_base = (mb0 & 63) + quad * 4;
        #pragma unroll
        for (int nt = 0; nt < 4; ++nt) {
            bool msk = (mode <= 1) && (qv[nt] >= sl);
            float v0 = msk ? 0.f : (acc[nt][0] + bias4[nt]) * oscale;
            float v1 = msk ? 0.f : (acc[nt][1] + bias4[nt]) * oscale;
            float v2 = msk ? 0.f : (acc[nt][2] + bias4[nt]) * oscale;
            float v3 = msk ? 0.f : (acc[nt][3] + bias4[nt]) * oscale;
            uint2 pk; pk.x = pack2(v0, v1); pk.y = pack2(v2, v3);
            *(uint2*)(outp + (((size_t)hh * T_SEQ + qv[nt]) << 6) + e_base) = pk;
        }
        #pragma unroll
        for (int ks = 0; ks < 8; ++ks) Acur[ks] = Anext[ks];
    }
}

// ============ per-head mean of V (coalesced) ================================
__global__ __launch_bounds__(256) void meanv_kernel(const ushort_t* __restrict__ Vh,
                                                    float* __restrict__ mv) {
    __shared__ float red[32][72];
    const int h = blockIdx.x, tid = threadIdx.x;
    const int g = tid >> 3;            // 0..31 row-group
    const int es = (tid & 7) * 8;      // e-slice
    const ushort_t* p = Vh + (size_t)h * T_SEQ * DE + (size_t)g * DE + es;
    float s[8] = {};
    for (int k = 0; k < 64; ++k) {
        uint4 u = *(const uint4*)(p + (size_t)k * 32 * DE);
        const ushort_t* w = (const ushort_t*)&u;
        #pragma unroll
        for (int i = 0; i < 8; ++i) s[i] += bf2f(w[i]);
    }
    #pragma unroll
    for (int i = 0; i < 8; ++i) red[g][es + i] = s[i];
    __syncthreads();
    if (tid < 64) {
        float t = 0.f;
        #pragma unroll
        for (int gg = 0; gg < 32; ++gg) t += red[gg][tid];
        mv[h * DE + tid] = t * (1.0f / T_SEQ);
    }
}

// ============ banded flash attention, bf16 MFMA, no-max softmax =============
__global__ __launch_bounds__(256) void attn_mfma_kernel(
    const ushort_t* __restrict__ Qh, const ushort_t* __restrict__ Kh,
    const ushort_t* __restrict__ Vh, const float* __restrict__ thr_g,
    const float* __restrict__ meanv, const int* __restrict__ seq_len,
    const float* __restrict__ theta, ushort_t* __restrict__ ctxb)
{
    __shared__ ushort_t Ks [64][72];   // [j][e]
    __shared__ ushort_t VTs[64][72];   // [e][j]  (transposed at staging)
    __shared__ ushort_t Ps [4][16][72];
    __shared__ float thrs[THR_N];

    const int tid  = threadIdx.x;
    const int wave = tid >> 6;
    const int lane = tid & 63;
    const int quad = lane >> 4;
    const int l15  = lane & 15;
    const int h  = blockIdx.y;
    const int b  = h >> 2;
    const int q0 = blockIdx.x * 64;
    const int sl = seq_len[b];
    ushort_t* outbase = ctxb + ((size_t)b * T_SEQ + q0) * DIM + (size_t)(h & 3) * 64;

    if (q0 >= sl) {   // whole tile masked: softmax uniform over ALL 2048 -> meanV
        #pragma unroll
        for (int nt = 0; nt < 4; ++nt) {
            ushort_t mval = f2bf(meanv[h * DE + l15 + 16 * nt]);
            #pragma unroll
            for (int r = 0; r < 4; ++r) {
                int row = wave * 16 + quad * 4 + r;
                outbase[(size_t)row * DIM + l15 + 16 * nt] = mval;
            }
        }
        return;
    }

    for (int i = tid; i < THR_N; i += 256) thrs[i] = thr_g[i];
    const float thv = theta[0];
    const float negInv = -1.0f / (thv * thv);

    short8 qa0, qa1;
    {
        const ushort_t* qp = Qh + ((size_t)h * T_SEQ + q0 + wave * 16 + l15) * DE + quad * 8;
        qa0 = *(const short8*)(qp);
        qa1 = *(const short8*)(qp + 32);
    }

    float l_acc[4] = {0.f, 0.f, 0.f, 0.f};
    floatx4 cacc[4];
    #pragma unroll
    for (int nt = 0; nt < 4; ++nt) cacc[nt] = (floatx4){0.f, 0.f, 0.f, 0.f};

    int jlo = q0 - BAND;      if (jlo < 0) jlo = 0;
    int jhi = q0 + 63 + BAND; if (jhi > sl - 1) jhi = sl - 1;   // j>=sl: all p=0, skip

    for (int jt = jlo >> 6; jt <= jhi >> 6; ++jt) {
        const int j0 = jt << 6;
        __syncthreads();
        {   // stage K (vector) and V (transposed, scalar b16 writes)
            const ushort_t* ksrc = Kh + ((size_t)h * T_SEQ + j0) * DE;
            const ushort_t* vsrc = Vh + ((size_t)h * T_SEQ + j0) * DE;
            #pragma unroll
            for (int rnd = 0; rnd < 2; ++rnd) {
                int flat = rnd * 256 + tid;
                int row = flat >> 3, c8 = (flat & 7) * 8;
                *(uint4*)&Ks[row][c8] = *(const uint4*)(ksrc + (size_t)row * DE + c8);
            }
            union { uint4 u4[2]; ushort_t us[16]; } vv;
            vv.u4[0] = *(const uint4*)(vsrc + (size_t)lane * DE + wave * 16);
            vv.u4[1] = *(const uint4*)(vsrc + (size_t)lane * DE + wave * 16 + 8);
            #pragma unroll
            for (int k = 0; k < 16; ++k) VTs[wave * 16 + k][lane] = vv.us[k];
        }
        __syncthreads();

        // S = Q K^T (already scaled by 1/sqrt(T) via Q)
        floatx4 S[4];
        #pragma unroll
        for (int nt = 0; nt < 4; ++nt) {
            short8 kb0 = *(const short8*)&Ks[l15 + 16 * nt][quad * 8];
            short8 kb1 = *(const short8*)&Ks[l15 + 16 * nt][32 + quad * 8];
            floatx4 z = {0.f, 0.f, 0.f, 0.f};
            z = __builtin_amdgcn_mfma_f32_16x16x32_bf16(qa0, kb0, z, 0, 0, 0);
            z = __builtin_amdgcn_mfma_f32_16x16x32_bf16(qa1, kb1, z, 0, 0, 0);
            S[nt] = z;
        }

        // weights p = exp(s*punish) (no max-subtract; shift-invariant softmax)
        const int off = j0 - q0;
        float p[4][4];
        if (off >= -320 && off <= 320) {
            // FAST: |delta|<=383 -> punish f32-normal via __expf; excl <=> j>=sl
            #pragma unroll
            for (int nt = 0; nt < 4; ++nt) {
                int jg = j0 + l15 + 16 * nt;
                bool jv = (jg < sl);
                #pragma unroll
                for (int r = 0; r < 4; ++r) {
                    int qg = q0 + wave * 16 + quad * 4 + r;
                    float df = (float)(jg - qg);
                    float pd = __expf(df * df * negInv);
                    float av = S[nt][r] * pd;
                    av = jv ? av : -1e30f;
                    p[nt][r] = __expf(av);
                }
            }
        } else {
            // BOUNDARY: |delta|>=321 -> exp(av)==1.0f exactly; p = included? 1:0
            #pragma unroll
            for (int nt = 0; nt < 4; ++nt) {
                int jg = j0 + l15 + 16 * nt;
                #pragma unroll
                for (int r = 0; r < 4; ++r) {
                    int qg = q0 + wave * 16 + quad * 4 + r;
                    int ad = abs(jg - qg);
                    float t = thrs[ad];
                    p[nt][r] = (fabsf(S[nt][r]) > t) ? 1.0f : 0.0f;
                }
            }
        }

        #pragma unroll
        for (int nt = 0; nt < 4; ++nt)
            #pragma unroll
            for (int r = 0; r < 4; ++r) {
                l_acc[r] += p[nt][r];
                Ps[wave][quad * 4 + r][l15 + 16 * nt] = f2bf(p[nt][r]);
            }

        // PV (wave-private P round-trip; no alpha rescale needed)
        short8 pa0 = *(const short8*)&Ps[wave][l15][quad * 8];
        short8 pa1 = *(const short8*)&Ps[wave][l15][32 + quad * 8];
        #pragma unroll
        for (int nt = 0; nt < 4; ++nt) {
            short8 vb0 = *(const short8*)&VTs[l15 + 16 * nt][quad * 8];
            short8 vb1 = *(const short8*)&VTs[l15 + 16 * nt][32 + quad * 8];
            floatx4 c = cacc[nt];
            c = __builtin_amdgcn_mfma_f32_16x16x32_bf16(pa0, vb0, c, 0, 0, 0);
            c = __builtin_amdgcn_mfma_f32_16x16x32_bf16(pa1, vb1, c, 0, 0, 0);
            cacc[nt] = c;
        }
    }

    // final: reduce l across the 16-lane row group, divide, store
    #pragma unroll
    for (int r = 0; r < 4; ++r) {
        float lv = l_acc[r];
        #pragma unroll
        for (int o = 1; o <= 8; o <<= 1) lv += __shfl_xor(lv, o);
        l_acc[r] = 1.0f / lv;
    }
    #pragma unroll
    for (int nt = 0; nt < 4; ++nt) {
        #pragma unroll
        for (int r = 0; r < 4; ++r) {
            int row = wave * 16 + quad * 4 + r;
            int qg = q0 + row;
            float o = cacc[nt][r] * l_acc[r];
            if (qg >= sl) o = meanv[h * DE + l15 + 16 * nt];
            outbase[(size_t)row * DIM + l15 + 16 * nt] = f2bf(o);
        }
    }
}

// ============ output projection + bias + residual (zero-LDS MFMA) ===========
__global__ __launch_bounds__(256, 2) void proj_o_mfma(
    const ushort_t* __restrict__ ctx, const ushort_t* __restrict__ wb,
    const float* __restrict__ bo, const float* __restrict__ x,
    float* __restrict__ out)
{
    const int wave = threadIdx.x >> 6, lane = threadIdx.x & 63;
    const int quad = lane >> 4, l15 = lane & 15;
    const int task = blockIdx.x * 4 + wave;      // 1024 tasks
    const int nt64 = task & 3;
    const int mstrip = task >> 2;
    const int n0 = nt64 * 64;
    const ushort_t* Wp = wb + (size_t)3 * 65536; // wo
    const int m0 = mstrip * 64;

    short8 Bf[4][8];
    #pragma unroll
    for (int nt = 0; nt < 4; ++nt) {
        int nrow = n0 + nt * 16 + l15;
        #pragma unroll
        for (int ks = 0; ks < 8; ++ks)
            Bf[nt][ks] = *(const short8*)(Wp + (size_t)nrow * 256 + ks * 32 + quad * 8);
    }
    float bias4[4];
    #pragma unroll
    for (int nt = 0; nt < 4; ++nt) bias4[nt] = bo[n0 + nt * 16 + l15];

    short8 Acur[8];
    #pragma unroll
    for (int ks = 0; ks < 8; ++ks)
        Acur[ks] = *(const short8*)(ctx + (size_t)(m0 + l15) * 256 + ks * 32 + quad * 8);

    #pragma unroll
    for (int mb = 0; mb < 4; ++mb) {
        const int mb0 = m0 + mb * 16;
        short8 Anext[8];
        if (mb < 3) {
            #pragma unroll
            for (int ks = 0; ks < 8; ++ks)
                Anext[ks] = *(const short8*)(ctx + (size_t)(mb0 + 16 + l15) * 256 + ks * 32 + quad * 8);
        }
        floatx4 acc[4];
        #pragma unroll
        for (int nt = 0; nt < 4; ++nt) acc[nt] = (floatx4){0.f, 0.f, 0.f, 0.f};
        #pragma unroll
        for (int ks = 0; ks < 8; ++ks)
            #pragma unroll
            for (int nt = 0; nt < 4; ++nt)
                acc[nt] = __builtin_amdgcn_mfma_f32_16x16x32_bf16(Acur[ks], Bf[nt][ks], acc[nt], 0, 0, 0);
        #pragma unroll
        for (int nt = 0; nt < 4; ++nt) {
            int d = n0 + nt * 16 + l15;
            #pragma unroll
            for (int r = 0; r < 4; ++r) {
                size_t mi = (size_t)(mb0 + quad * 4 + r) * 256 + d;
                out[mi] = acc[nt][r] + bias4[nt] + x[mi];
            }
        }
        #pragma unroll
        for (int ks = 0; ks < 8; ++ks) Acur[ks] = Anext[ks];
    }
}

extern "C" void kernel_launch(void* const* d_in, const int* in_sizes, int n_in,
                              void* d_out, int out_size, void* d_ws, size_t ws_size,
                              hipStream_t stream)
{
    (void)in_sizes; (void)n_in; (void)out_size; (void)ws_size;
    const float* x  = (const float*)d_in[0];
    const int*   sl = (const int*)d_in[1];
    const float* wq = (const float*)d_in[2];
    const float* bq = (const float*)d_in[3];
    const float* wk = (const float*)d_in[4];
    const float* bk = (const float*)d_in[5];
    const float* wv = (const float*)d_in[6];
    const float* bv = (const float*)d_in[7];
    const float* wo = (const float*)d_in[8];
    const float* bo = (const float*)d_in[9];
    const float* th = (const float*)d_in[10];
    float* out = (float*)d_out;

    char* ws = (char*)d_ws;
    const size_t SZH = (size_t)M_ROWS * DIM * sizeof(ushort_t);  // 8 MiB
    ushort_t* xb  = (ushort_t*)(ws);
    ushort_t* wb  = (ushort_t*)(ws + SZH);                       // 512 KiB
    ushort_t* Qh  = (ushort_t*)(ws + SZH + 524288);
    ushort_t* Kh  = (ushort_t*)(ws + 2*SZH + 524288);
    ushort_t* Vh  = (ushort_t*)(ws + 3*SZH + 524288);
    ushort_t* Cb  = (ushort_t*)(ws + 4*SZH + 524288);
    float*    Mv  = (float*)   (ws + 5*SZH + 524288);
    float*    Thr = (float*)   (ws + 5*SZH + 524288 + 16384);

    prep_kernel<<<dim3(2179), dim3(256), 0, stream>>>(x, wq, wk, wv, wo, th, xb, wb, Thr);
    proj_qkv_mfma<<<dim3(768), dim3(256), 0, stream>>>(xb, wb, bq, bk, bv, sl, Qh, Kh, Vh);
    meanv_kernel<<<dim3(NH), dim3(256), 0, stream>>>(Vh, Mv);
    attn_mfma_kernel<<<dim3(T_SEQ/64, NH), dim3(256), 0, stream>>>(Qh, Kh, Vh, Thr, Mv, sl, th, Cb);
    proj_o_mfma<<<dim3(256), dim3(256), 0, stream>>>(Cb, wb, bo, x, out);
}

// Round 5
// 190.973 us; speedup vs baseline: 5.4649x; 1.0382x over previous
//
#include <hip/hip_runtime.h>
#include <math.h>
#include <stdint.h>

#define B_SZ   8
#define T_SEQ  2048
#define DIM    256
#define NH     32            // B*E
#define DE     64
#define BAND   509           // |j-i|<=509 can have nonzero f32 punish (denormals)
#define THR_N  641           // tables indexed by |delta|
#define M_ROWS (B_SZ * T_SEQ)

typedef __attribute__((ext_vector_type(8))) short short8;   // 8 bf16 (4 VGPRs)
typedef __attribute__((ext_vector_type(4))) float floatx4;  // MFMA C/D frag
typedef unsigned short ushort_t;

__device__ __forceinline__ ushort_t f2bf(float x) {   // RNE f32->bf16
    unsigned u = __float_as_uint(x);
    u += 0x7fffu + ((u >> 16) & 1u);
    return (ushort_t)(u >> 16);
}
__device__ __forceinline__ float bf2f(ushort_t b) {
    return __uint_as_float(((unsigned)b) << 16);
}
__device__ __forceinline__ unsigned pack2(float a, float b) {
    return (unsigned)f2bf(a) | ((unsigned)f2bf(b) << 16);
}

// ============ prep: x,w -> bf16; thr + pdf tables ===========================
// grid: [0,2048) x-chunks, [2048,2176) w-chunks, [2176,2179) tables
__global__ __launch_bounds__(256) void prep_kernel(
    const float* __restrict__ x,
    const float* __restrict__ wq, const float* __restrict__ wk,
    const float* __restrict__ wv, const float* __restrict__ wo,
    const float* __restrict__ theta,
    ushort_t* __restrict__ xb, ushort_t* __restrict__ wb,
    float* __restrict__ thr_g, float* __restrict__ pdf_g)
{
    const int bid = blockIdx.x, tid = threadIdx.x;
    if (bid < 2048) {
        size_t i8 = ((size_t)bid * 256 + tid) * 8;
        float4 a = *(const float4*)(x + i8);
        float4 b = *(const float4*)(x + i8 + 4);
        uint4 o;
        o.x = pack2(a.x, a.y); o.y = pack2(a.z, a.w);
        o.z = pack2(b.x, b.y); o.w = pack2(b.z, b.w);
        *(uint4*)(xb + i8) = o;
    } else if (bid < 2176) {
        size_t w8 = ((size_t)(bid - 2048) * 256 + tid) * 8;
        int which = (int)(w8 >> 16);
        const float* src = (which == 0) ? wq : (which == 1) ? wk : (which == 2) ? wv : wo;
        size_t off = w8 & 65535;
        float4 a = *(const float4*)(src + off);
        float4 b = *(const float4*)(src + off + 4);
        uint4 o;
        o.x = pack2(a.x, a.y); o.y = pack2(a.z, a.w);
        o.z = pack2(b.x, b.y); o.w = pack2(b.z, b.w);
        *(uint4*)(wb + w8) = o;
    } else {
        int i = (bid - 2176) * 256 + tid;
        if (i >= THR_N) return;
        float df  = (float)i;
        float th  = theta[0];
        float arg = (-(df * df)) / (th * th);      // exact same f32 ops as numpy
        double pdd = exp((double)arg);
        double outv;                               // f32-RNE value incl. denormals
        if (pdd < 1.17549435082228751e-38) {
            outv = rint(pdd * 0x1p149) * 0x1p-149;
        } else {
            outv = (double)(float)pdd;
        }
        // exclusion: RN32(s*pd)==0  <=>  |s| <= 2^-150/pd
        thr_g[i] = (outv == 0.0) ? __builtin_inff() : (float)(0x1p-150 / outv);
        pdf_g[i] = (float)outv;
    }
}

// ============ QKV projection: zero-LDS MFMA GEMM (Q pre-scaled 1/sqrt(T)) ===
// head map: h=b*4+d/64, q=(d%64)*32+t/64, e=t%64.  Qh/Kh masked q>=sl -> 0.
__global__ __launch_bounds__(256, 2) void proj_qkv_mfma(
    const ushort_t* __restrict__ xb, const ushort_t* __restrict__ wb,
    const float* __restrict__ bq, const float* __restrict__ bk,
    const float* __restrict__ bv, const int* __restrict__ seq_len,
    ushort_t* __restrict__ Qh, ushort_t* __restrict__ Kh, ushort_t* __restrict__ Vh)
{
    const int wave = threadIdx.x >> 6, lane = threadIdx.x & 63;
    const int quad = lane >> 4, l15 = lane & 15;
    const int task = blockIdx.x * 4 + wave;      // 3072 tasks
    const int nt64 = task % 12;
    const int mstrip = task / 12;
    const int mode = nt64 >> 2;                  // 0:Q 1:K 2:V
    const int nloc_base = (nt64 & 3) * 64;       // d within [0,256)
    const ushort_t* Wp = wb + (size_t)mode * 65536;
    const int m0 = mstrip * 64;
    const int bb = m0 >> 11;
    const int th0 = (m0 >> 6) & 31;
    const int sl = seq_len[bb];
    ushort_t* outp = (mode == 0) ? Qh : (mode == 1) ? Kh : Vh;
    const float* bias = (mode == 0) ? bq : (mode == 1) ? bk : bv;
    const int hh = bb * 4 + (nloc_base >> 6);
    const float oscale = (mode == 0) ? 0.022097086912079612f : 1.0f;  // 1/sqrt(2048)

    short8 Bf[4][8];
    #pragma unroll
    for (int nt = 0; nt < 4; ++nt) {
        int nrow = nloc_base + nt * 16 + l15;
        #pragma unroll
        for (int ks = 0; ks < 8; ++ks)
            Bf[nt][ks] = *(const short8*)(Wp + (size_t)nrow * 256 + ks * 32 + quad * 8);
    }
    float bias4[4]; int qv[4];
    #pragma unroll
    for (int nt = 0; nt < 4; ++nt) {
        int dl = nloc_base + nt * 16 + l15;
        bias4[nt] = bias[dl];
        qv[nt] = (dl & 63) * 32 + th0;
    }

    short8 Acur[8];
    #pragma unroll
    for (int ks = 0; ks < 8; ++ks)
        Acur[ks] = *(const short8*)(xb + (size_t)(m0 + l15) * 256 + ks * 32 + quad * 8);

    #pragma unroll
    for (int mb = 0; mb < 4; ++mb) {
        const int mb0 = m0 + mb * 16;
        short8 Anext[8];
        if (mb < 3) {
            #pragma unroll
            for (int ks = 0; ks < 8; ++ks)
                Anext[ks] = *(const short8*)(xb + (size_t)(mb0 + 16 + l15) * 256 + ks * 32 + quad * 8);
        }
        floatx4 acc[4];
        #pragma unroll
        for (int nt = 0; nt < 4; ++nt) acc[nt] = (floatx4){0.f, 0.f, 0.f, 0.f};
        #pragma unroll
        for (int ks = 0; ks < 8; ++ks)
            #pragma unroll
            for (int nt = 0; nt < 4; ++nt)
                acc[nt] = __builtin_amdgcn_mfma_f32_16x16x32_bf16(Acur[ks], Bf[nt][ks], acc[nt], 0, 0, 0);
        const int e_base = (mb0 & 63) + quad * 4;
        #pragma unroll
        for (int nt = 0; nt < 4; ++nt) {
            bool msk = (mode <= 1) && (qv[nt] >= sl);
            float v0 = msk ? 0.f : (acc[nt][0] + bias4[nt]) * oscale;
            float v1 = msk ? 0.f : (acc[nt][1] + bias4[nt]) * oscale;
            float v2 = msk ? 0.f : (acc[nt][2] + bias4[nt]) * oscale;
            float v3 = msk ? 0.f : (acc[nt][3] + bias4[nt]) * oscale;
            uint2 pk; pk.x = pack2(v0, v1); pk.y = pack2(v2, v3);
            *(uint2*)(outp + (((size_t)hh * T_SEQ + qv[nt]) << 6) + e_base) = pk;
        }
        #pragma unroll
        for (int ks = 0; ks < 8; ++ks) Acur[ks] = Anext[ks];
    }
}

// ============ per-head SUM of V (coalesced, 8 blocks/head, atomic) ==========
// Mv must be zeroed before launch; holds column sums (divide by T at use site)
__global__ __launch_bounds__(256) void meanv_partial(const ushort_t* __restrict__ Vh,
                                                     float* __restrict__ mv) {
    __shared__ float red[32][72];
    const int blk = blockIdx.x;          // 256 = 32 heads x 8 chunks
    const int h = blk >> 3, chunk = blk & 7;
    const int tid = threadIdx.x;
    const int r0 = tid >> 3;             // 0..31
    const int es = (tid & 7) * 8;        // e-slice
    const ushort_t* p = Vh + ((size_t)h * T_SEQ + chunk * 256 + r0) * DE + es;
    float s[8] = {};
    #pragma unroll
    for (int k = 0; k < 8; ++k) {        // rows r0 + 32*k
        uint4 u = *(const uint4*)(p + (size_t)k * 32 * DE);
        const ushort_t* w = (const ushort_t*)&u;
        #pragma unroll
        for (int i = 0; i < 8; ++i) s[i] += bf2f(w[i]);
    }
    #pragma unroll
    for (int i = 0; i < 8; ++i) red[r0][es + i] = s[i];
    __syncthreads();
    if (tid < 64) {
        float t = 0.f;
        #pragma unroll
        for (int g = 0; g < 32; ++g) t += red[g][tid];
        atomicAdd(&mv[h * DE + tid], t);
    }
}

// ============ banded flash attention: swizzled, prefetched, pdf-table =======
__global__ __launch_bounds__(256) void attn_mfma_kernel(
    const ushort_t* __restrict__ Qh, const ushort_t* __restrict__ Kh,
    const ushort_t* __restrict__ Vh, const float* __restrict__ thr_g,
    const float* __restrict__ pdf_g, const float* __restrict__ meanv,
    const int* __restrict__ seq_len, ushort_t* __restrict__ ctxb)
{
    __shared__ ushort_t Ks [64][72];   // [j][e]
    __shared__ ushort_t VTs[64][72];   // [e][j]  (transposed at staging)
    __shared__ ushort_t Ps [4][16][72];
    __shared__ float pdfs[384];        // punish f32, |delta| 0..383 (fast path)
    __shared__ float thrs[320];        // thr[|delta|-321], 321..640 (boundary)

    const int tid  = threadIdx.x;
    const int wave = tid >> 6;
    const int lane = tid & 63;
    const int quad = lane >> 4;
    const int l15  = lane & 15;
    // XCD swizzle: same head's 32 q-blocks share one XCD; batches interleaved
    const int bid   = blockIdx.x;
    const int inner = bid >> 3;
    const int h  = ((inner >> 5) << 3) | (bid & 7);
    const int q0 = (inner & 31) * 64;
    const int b  = h >> 2;
    const int sl = seq_len[b];
    const float invT = 1.0f / (float)T_SEQ;
    ushort_t* outbase = ctxb + ((size_t)b * T_SEQ + q0) * DIM + (size_t)(h & 3) * 64;

    if (q0 >= sl) {   // whole tile masked: softmax uniform over ALL 2048 -> meanV
        #pragma unroll
        for (int nt = 0; nt < 4; ++nt) {
            ushort_t mval = f2bf(meanv[h * DE + l15 + 16 * nt] * invT);
            #pragma unroll
            for (int r = 0; r < 4; ++r) {
                int row = wave * 16 + quad * 4 + r;
                outbase[(size_t)row * DIM + l15 + 16 * nt] = mval;
            }
        }
        return;
    }

    for (int i = tid; i < 384; i += 256) pdfs[i] = pdf_g[i];
    for (int i = tid; i < 320; i += 256) thrs[i] = thr_g[321 + i];

    short8 qa0, qa1;
    {
        const ushort_t* qp = Qh + ((size_t)h * T_SEQ + q0 + wave * 16 + l15) * DE + quad * 8;
        qa0 = *(const short8*)(qp);
        qa1 = *(const short8*)(qp + 32);
    }

    float l_acc[4] = {0.f, 0.f, 0.f, 0.f};
    floatx4 cacc[4];
    #pragma unroll
    for (int nt = 0; nt < 4; ++nt) cacc[nt] = (floatx4){0.f, 0.f, 0.f, 0.f};

    int jlo = q0 - BAND;      if (jlo < 0) jlo = 0;
    int jhi = q0 + 63 + BAND; if (jhi > sl - 1) jhi = sl - 1;   // j>=sl: all p=0
    const int jt0 = jlo >> 6, jt1 = jhi >> 6;

    // register prefetch of K/V tile (hides global latency behind compute)
    const int krow = tid >> 3;           // 0..31
    const int kc8  = (tid & 7) * 8;
    uint4 kpre0, kpre1, vpre0, vpre1;
    {
        const ushort_t* ksrc = Kh + ((size_t)h * T_SEQ + (jt0 << 6)) * DE;
        const ushort_t* vsrc = Vh + ((size_t)h * T_SEQ + (jt0 << 6)) * DE;
        kpre0 = *(const uint4*)(ksrc + (size_t)krow * DE + kc8);
        kpre1 = *(const uint4*)(ksrc + (size_t)(krow + 32) * DE + kc8);
        vpre0 = *(const uint4*)(vsrc + (size_t)lane * DE + wave * 16);
        vpre1 = *(const uint4*)(vsrc + (size_t)lane * DE + wave * 16 + 8);
    }

    for (int jt = jt0; jt <= jt1; ++jt) {
        const int j0 = jt << 6;
        __syncthreads();
        *(uint4*)&Ks[krow][kc8]      = kpre0;
        *(uint4*)&Ks[krow + 32][kc8] = kpre1;
        {
            union { uint4 u4[2]; ushort_t us[16]; } vv;
            vv.u4[0] = vpre0; vv.u4[1] = vpre1;
            #pragma unroll
            for (int k = 0; k < 16; ++k) VTs[wave * 16 + k][lane] = vv.us[k];
        }
        __syncthreads();
        if (jt < jt1) {   // issue next tile's loads; they fly during compute
            const ushort_t* ksrc = Kh + ((size_t)h * T_SEQ + j0 + 64) * DE;
            const ushort_t* vsrc = Vh + ((size_t)h * T_SEQ + j0 + 64) * DE;
            kpre0 = *(const uint4*)(ksrc + (size_t)krow * DE + kc8);
            kpre1 = *(const uint4*)(ksrc + (size_t)(krow + 32) * DE + kc8);
            vpre0 = *(const uint4*)(vsrc + (size_t)lane * DE + wave * 16);
            vpre1 = *(const uint4*)(vsrc + (size_t)lane * DE + wave * 16 + 8);
        }

        // S = Q K^T (already scaled by 1/sqrt(T) via Q)
        floatx4 S[4];
        #pragma unroll
        for (int nt = 0; nt < 4; ++nt) {
            short8 kb0 = *(const short8*)&Ks[l15 + 16 * nt][quad * 8];
            short8 kb1 = *(const short8*)&Ks[l15 + 16 * nt][32 + quad * 8];
            floatx4 z = {0.f, 0.f, 0.f, 0.f};
            z = __builtin_amdgcn_mfma_f32_16x16x32_bf16(qa0, kb0, z, 0, 0, 0);
            z = __builtin_amdgcn_mfma_f32_16x16x32_bf16(qa1, kb1, z, 0, 0, 0);
            S[nt] = z;
        }

        // weights p = exp(s*punish) (no max-subtract; softmax shift-invariant)
        const int off = j0 - q0;
        float p[4][4];
        if (off >= -320 && off <= 320) {
            // FAST: |delta|<=383 -> punish from LDS table; excl <=> j>=sl
            #pragma unroll
            for (int nt = 0; nt < 4; ++nt) {
                int jg = j0 + l15 + 16 * nt;
                bool jv = (jg < sl);
                #pragma unroll
                for (int r = 0; r < 4; ++r) {
                    int qg = q0 + wave * 16 + quad * 4 + r;
                    float pd = pdfs[abs(jg - qg)];
                    float av = S[nt][r] * pd;
                    av = jv ? av : -1e30f;
                    p[nt][r] = __expf(av);
                }
            }
        } else {
            // BOUNDARY: |delta|>=321 -> exp(av)==1.0f exactly; p = included? 1:0
            // (masked j has S==0 -> p=0, correct)
            #pragma unroll
            for (int nt = 0; nt < 4; ++nt) {
                int jg = j0 + l15 + 16 * nt;
                #pragma unroll
                for (int r = 0; r < 4; ++r) {
                    int qg = q0 + wave * 16 + quad * 4 + r;
                    float t = thrs[abs(jg - qg) - 321];
                    p[nt][r] = (fabsf(S[nt][r]) > t) ? 1.0f : 0.0f;
                }
            }
        }

        #pragma unroll
        for (int nt = 0; nt < 4; ++nt)
            #pragma unroll
            for (int r = 0; r < 4; ++r) {
                l_acc[r] += p[nt][r];
                Ps[wave][quad * 4 + r][l15 + 16 * nt] = f2bf(p[nt][r]);
            }

        // PV (wave-private P round-trip; no rescale needed)
        short8 pa0 = *(const short8*)&Ps[wave][l15][quad * 8];
        short8 pa1 = *(const short8*)&Ps[wave][l15][32 + quad * 8];
        #pragma unroll
        for (int nt = 0; nt < 4; ++nt) {
            short8 vb0 = *(const short8*)&VTs[l15 + 16 * nt][quad * 8];
            short8 vb1 = *(const short8*)&VTs[l15 + 16 * nt][32 + quad * 8];
            floatx4 c = cacc[nt];
            c = __builtin_amdgcn_mfma_f32_16x16x32_bf16(pa0, vb0, c, 0, 0, 0);
            c = __builtin_amdgcn_mfma_f32_16x16x32_bf16(pa1, vb1, c, 0, 0, 0);
            cacc[nt] = c;
        }
    }

    // final: reduce l across the 16-lane row group, divide, store
    #pragma unroll
    for (int r = 0; r < 4; ++r) {
        float lv = l_acc[r];
        #pragma unroll
        for (int o = 1; o <= 8; o <<= 1) lv += __shfl_xor(lv, o);
        l_acc[r] = 1.0f / lv;
    }
    #pragma unroll
    for (int nt = 0; nt < 4; ++nt) {
        #pragma unroll
        for (int r = 0; r < 4; ++r) {
            int row = wave * 16 + quad * 4 + r;
            int qg = q0 + row;
            float o = cacc[nt][r] * l_acc[r];
            if (qg >= sl) o = meanv[h * DE + l15 + 16 * nt] * invT;
            outbase[(size_t)row * DIM + l15 + 16 * nt] = f2bf(o);
        }
    }
}

// ============ output projection + bias + residual (zero-LDS MFMA) ===========
__global__ __launch_bounds__(256, 2) void proj_o_mfma(
    const ushort_t* __restrict__ ctx, const ushort_t* __restrict__ wb,
    const float* __restrict__ bo, const float* __restrict__ x,
    float* __restrict__ out)
{
    const int wave = threadIdx.x >> 6, lane = threadIdx.x & 63;
    const int quad = lane >> 4, l15 = lane & 15;
    const int task = blockIdx.x * 4 + wave;      // 1024 tasks
    const int nt64 = task & 3;
    const int mstrip = task >> 2;
    const int n0 = nt64 * 64;
    const ushort_t* Wp = wb + (size_t)3 * 65536; // wo
    const int m0 = mstrip * 64;

    short8 Bf[4][8];
    #pragma unroll
    for (int nt = 0; nt < 4; ++nt) {
        int nrow = n0 + nt * 16 + l15;
        #pragma unroll
        for (int ks = 0; ks < 8; ++ks)
            Bf[nt][ks] = *(const short8*)(Wp + (size_t)nrow * 256 + ks * 32 + quad * 8);
    }
    float bias4[4];
    #pragma unroll
    for (int nt = 0; nt < 4; ++nt) bias4[nt] = bo[n0 + nt * 16 + l15];

    short8 Acur[8];
    #pragma unroll
    for (int ks = 0; ks < 8; ++ks)
        Acur[ks] = *(const short8*)(ctx + (size_t)(m0 + l15) * 256 + ks * 32 + quad * 8);

    #pragma unroll
    for (int mb = 0; mb < 4; ++mb) {
        const int mb0 = m0 + mb * 16;
        short8 Anext[8];
        if (mb < 3) {
            #pragma unroll
            for (int ks = 0; ks < 8; ++ks)
                Anext[ks] = *(const short8*)(ctx + (size_t)(mb0 + 16 + l15) * 256 + ks * 32 + quad * 8);
        }
        floatx4 acc[4];
        #pragma unroll
        for (int nt = 0; nt < 4; ++nt) acc[nt] = (floatx4){0.f, 0.f, 0.f, 0.f};
        #pragma unroll
        for (int ks = 0; ks < 8; ++ks)
            #pragma unroll
            for (int nt = 0; nt < 4; ++nt)
                acc[nt] = __builtin_amdgcn_mfma_f32_16x16x32_bf16(Acur[ks], Bf[nt][ks], acc[nt], 0, 0, 0);
        #pragma unroll
        for (int nt = 0; nt < 4; ++nt) {
            int d = n0 + nt * 16 + l15;
            #pragma unroll
            for (int r = 0; r < 4; ++r) {
                size_t mi = (size_t)(mb0 + quad * 4 + r) * 256 + d;
                out[mi] = acc[nt][r] + bias4[nt] + x[mi];
            }
        }
        #pragma unroll
        for (int ks = 0; ks < 8; ++ks) Acur[ks] = Anext[ks];
    }
}

extern "C" void kernel_launch(void* const* d_in, const int* in_sizes, int n_in,
                              void* d_out, int out_size, void* d_ws, size_t ws_size,
                              hipStream_t stream)
{
    (void)in_sizes; (void)n_in; (void)out_size; (void)ws_size;
    const float* x  = (const float*)d_in[0];
    const int*   sl = (const int*)d_in[1];
    const float* wq = (const float*)d_in[2];
    const float* bq = (const float*)d_in[3];
    const float* wk = (const float*)d_in[4];
    const float* bk = (const float*)d_in[5];
    const float* wv = (const float*)d_in[6];
    const float* bv = (const float*)d_in[7];
    const float* wo = (const float*)d_in[8];
    const float* bo = (const float*)d_in[9];
    const float* th = (const float*)d_in[10];
    float* out = (float*)d_out;

    char* ws = (char*)d_ws;
    const size_t SZH = (size_t)M_ROWS * DIM * sizeof(ushort_t);  // 8 MiB
    ushort_t* xb  = (ushort_t*)(ws);
    ushort_t* wb  = (ushort_t*)(ws + SZH);                       // 512 KiB
    ushort_t* Qh  = (ushort_t*)(ws + SZH + 524288);
    ushort_t* Kh  = (ushort_t*)(ws + 2*SZH + 524288);
    ushort_t* Vh  = (ushort_t*)(ws + 3*SZH + 524288);
    ushort_t* Cb  = (ushort_t*)(ws + 4*SZH + 524288);
    float*    Mv  = (float*)   (ws + 5*SZH + 524288);            // 8 KiB
    float*    Thr = (float*)   (ws + 5*SZH + 524288 + 8192);     // 4 KiB
    float*    Pdf = (float*)   (ws + 5*SZH + 524288 + 12288);    // 4 KiB

    hipMemsetAsync(Mv, 0, NH * DE * sizeof(float), stream);
    prep_kernel<<<dim3(2179), dim3(256), 0, stream>>>(x, wq, wk, wv, wo, th, xb, wb, Thr, Pdf);
    proj_qkv_mfma<<<dim3(768), dim3(256), 0, stream>>>(xb, wb, bq, bk, bv, sl, Qh, Kh, Vh);
    meanv_partial<<<dim3(256), dim3(256), 0, stream>>>(Vh, Mv);
    attn_mfma_kernel<<<dim3(T_SEQ/64 * NH), dim3(256), 0, stream>>>(Qh, Kh, Vh, Thr, Pdf, Mv, sl, Cb);
    proj_o_mfma<<<dim3(256), dim3(256), 0, stream>>>(Cb, wb, bo, x, out);
}